// Round 8
// baseline (301.989 us; speedup 1.0000x reference)
//
#include <hip/hip_runtime.h>
#include <stdint.h>

// Problem constants
#define B_   2
#define SQ   2048
#define H    1024
#define NH   16
#define HN   64
#define T_TOK 4096          // sq*b tokens
#define N3H  3072           // 3*h

typedef __bf16 bf16x8 __attribute__((ext_vector_type(8)));
typedef float  f32x4  __attribute__((ext_vector_type(4)));

#define MFMA16(a, b, c) __builtin_amdgcn_mfma_f32_16x16x32_bf16((a), (b), (c), 0, 0, 0)

// s_waitcnt lgkmcnt(0), vmcnt/expcnt left open (intrinsic form).
#define LGKM_DRAIN() do { \
  __builtin_amdgcn_s_waitcnt(0xC07F); \
  __builtin_amdgcn_wave_barrier(); \
} while (0)

__device__ __forceinline__ uint16_t f2bf_u(float f) {
  union { float f; uint32_t u; } v; v.f = f;
  uint32_t u = v.u;
  u += 0x7fffu + ((u >> 16) & 1u);   // RNE (no NaN inputs here)
  return (uint16_t)(u >> 16);
}

__device__ __forceinline__ bf16x8 ldb8(const uint16_t* p) {
  return *reinterpret_cast<const bf16x8*>(p);
}

// async global->LDS, 16B per lane. LDS dest = wave-uniform base + lane*16.
__device__ __forceinline__ void gll16(const uint16_t* g, uint16_t* l) {
  __builtin_amdgcn_global_load_lds(
      (const __attribute__((address_space(1))) uint32_t*)g,
      (__attribute__((address_space(3))) uint32_t*)l, 16, 0, 0);
}

// ---------------------------------------------------------------------------
// Kernel 1: fp32 -> bf16, 4 elements/thread.
// ---------------------------------------------------------------------------
__global__ __launch_bounds__(256) void convert_kernel(
    const float* __restrict__ x, const float* __restrict__ wqkv,
    const float* __restrict__ wproj,
    uint16_t* __restrict__ xb, uint16_t* __restrict__ wqkvb,
    uint16_t* __restrict__ wprojb) {
  const int XT4 = (T_TOK * H) / 4;   // 1048576
  const int WQ4 = (N3H * H) / 4;     // 786432
  int i4 = blockIdx.x * 256 + threadIdx.x;
  const float* src;
  uint16_t* dst;
  if (i4 < XT4) {
    int i = i4 * 4;
    int t = i >> 10, c = i & 1023;
    int bi = t & 1, s = t >> 1;
    src = x + (bi * SQ + s) * H + c;
    dst = xb + i;
  } else if (i4 < XT4 + WQ4) {
    int j = (i4 - XT4) * 4;
    src = wqkv + j; dst = wqkvb + j;
  } else {
    int j = (i4 - XT4 - WQ4) * 4;
    src = wproj + j; dst = wprojb + j;
  }
  float4 v = *(const float4*)src;
  ushort4 o;
  o.x = f2bf_u(v.x); o.y = f2bf_u(v.y); o.z = f2bf_u(v.z); o.w = f2bf_u(v.w);
  *(ushort4*)dst = o;
}

// ---------------------------------------------------------------------------
// Kernel 2: QKV GEMM, m97 structure + wave-uniform coalesced epilogue
// (unchanged from r7).
// ---------------------------------------------------------------------------
__global__ __launch_bounds__(256) void gemm_qkv_kernel(
    const uint16_t* __restrict__ xb, const uint16_t* __restrict__ wb,
    uint16_t* __restrict__ Qb, uint16_t* __restrict__ Kb,
    uint16_t* __restrict__ Vtb) {
  const int lane = threadIdx.x & 63;
  const int wave = threadIdx.x >> 6;
  const int quad = lane >> 4, l16 = lane & 15;
  const int wm = wave >> 1, wn = wave & 1;
  const int row0 = blockIdx.y * 128, col0 = blockIdx.x * 128;

  // union: staging (16 KB) and epilogue scratch (4 x 9728 B = 38912 B)
  __shared__ __align__(16) char smem[4 * 64 * 76 * 2];
  uint16_t* sA = (uint16_t*)smem;            // 128*32
  uint16_t* sB = (uint16_t*)(smem + 8192);   // 128*32
  uint16_t* W  = (uint16_t*)(smem) + wave * (64 * 76);

  const int lrow = lane >> 2;        // 0..15
  const int lk   = (lane & 3) * 8;   // k-chunk (8 elems = 16B)

  f32x4 acc[4][4];
#pragma unroll
  for (int i = 0; i < 4; ++i)
#pragma unroll
    for (int j = 0; j < 4; ++j) acc[i][j] = (f32x4){0.f, 0.f, 0.f, 0.f};

  for (int k0 = 0; k0 < H; k0 += 32) {
#pragma unroll
    for (int c = 0; c < 2; ++c) {
      int g = c * 4 + wave;
      gll16(xb + (size_t)(row0 + g * 16 + lrow) * H + k0 + lk, sA + g * 512);
      gll16(wb + (size_t)(col0 + g * 16 + lrow) * H + k0 + lk, sB + g * 512);
    }
    __syncthreads();
    bf16x8 af[4], bfr[4];
#pragma unroll
    for (int mt = 0; mt < 4; ++mt)
      af[mt] = ldb8(sA + (wm * 64 + mt * 16 + l16) * 32 + quad * 8);
#pragma unroll
    for (int nt = 0; nt < 4; ++nt)
      bfr[nt] = ldb8(sB + (wn * 64 + nt * 16 + l16) * 32 + quad * 8);
#pragma unroll
    for (int mt = 0; mt < 4; ++mt)
#pragma unroll
      for (int nt = 0; nt < 4; ++nt)
        acc[mt][nt] = MFMA16(af[mt], bfr[nt], acc[mt][nt]);
    __syncthreads();   // also protects smem reuse by the epilogue below
  }

  // ---- epilogue (wave-uniform routing; no divs, no branches per element) ---
  const int c0 = col0 + wn * 64;       // 64-aligned
  const int cm = c0 >> 6;              // 0..47
  const int hd = cm / 3;               // head (compile-time magic-mul)
  const int which = cm - hd * 3;       // 0=Q 1=K 2=V
  const int t0 = row0 + wm * 64;

  if (which < 2) {
    // LDS tile [t_local][d], stride 76
#pragma unroll
    for (int mt = 0; mt < 4; ++mt)
#pragma unroll
      for (int nt = 0; nt < 4; ++nt)
#pragma unroll
        for (int r = 0; r < 4; ++r)
          W[(mt * 16 + quad * 4 + r) * 76 + nt * 16 + l16] = f2bf_u(acc[mt][nt][r]);
    LGKM_DRAIN();
    uint16_t* dstb = (which == 0) ? Qb : Kb;
    const int t8 = lane >> 3, d0 = (lane & 7) * 8;
#pragma unroll
    for (int it = 0; it < 8; ++it) {
      int tl = it * 8 + t8;
      int t = t0 + tl;
      int s = t >> 1;
      int n = (t & 1) * NH + hd;
      bf16x8 vv = ldb8(W + tl * 76 + d0);
      *(bf16x8*)(dstb + (size_t)(n * SQ + s) * HN + d0) = vv;
    }
  } else {
    // V: LDS tile [d][bi*32 + s_local], stride 76; packed u32 writes
    uint32_t* W32 = (uint32_t*)W;
#pragma unroll
    for (int mt = 0; mt < 4; ++mt)
#pragma unroll
      for (int nt = 0; nt < 4; ++nt) {
        int base = (nt * 16 + l16) * 76 + mt * 8 + quad * 2;   // even
        W32[base >> 1] =
            (uint32_t)f2bf_u(acc[mt][nt][0]) | ((uint32_t)f2bf_u(acc[mt][nt][2]) << 16);
        W32[(base >> 1) + 16] =
            (uint32_t)f2bf_u(acc[mt][nt][1]) | ((uint32_t)f2bf_u(acc[mt][nt][3]) << 16);
      }
    LGKM_DRAIN();
    const int dl = lane >> 3;                 // 0..7
    const int bi = (lane >> 2) & 1;
    const int sc = (lane & 3) * 8;
    const int s0 = (row0 >> 1) + wm * 32;
    const int n = bi * NH + hd;
#pragma unroll
    for (int it = 0; it < 8; ++it) {
      int d = it * 8 + dl;
      bf16x8 vv = ldb8(W + d * 76 + bi * 32 + sc);
      *(bf16x8*)(Vtb + (size_t)(n * HN + d) * SQ + s0 + sc) = vv;
    }
  }
}

// ---------------------------------------------------------------------------
// Kernel 3: flash attention, k-split x2 + LDS K/V staging. NEW: P tiles
// alias the (dead-after-QK) K-stage region with the same XOR-row swizzle,
// cutting LDS 51200 -> 32768 B. 4 blocks/CU x 8 waves = 32 waves/CU (100%
// slot fill) and the 1024-block grid completes in EXACTLY one pass (r6/r7
// ran 1.33 passes at 3 blocks/CU — ~15 us of tail on a quarter-full GPU).
// Costs one extra barrier/iter (3 total): all waves' K ds_reads must
// complete before P overwrites the K tile. Arithmetic bit-identical.
// ---------------------------------------------------------------------------
__global__ __launch_bounds__(512, 8) void attn_kernel(
    const uint16_t* __restrict__ Qb, const uint16_t* __restrict__ Kb,
    const uint16_t* __restrict__ Vtb, uint16_t* __restrict__ ctxb) {
  const int lane = threadIdx.x & 63;
  const int wave = threadIdx.x >> 6;        // 0..7
  const int quad = lane >> 4, l16 = lane & 15;
  const int head  = blockIdx.x;   // n = bi*16 + hd
  const int qtile = blockIdx.y;
  const int wq = wave & 3;                  // q-subtile
  const int hf = wave >> 2;                 // k-range half
  const int q0 = qtile * 64 + wq * 16;

  const uint16_t* Qh = Qb + (size_t)head * SQ * HN;
  const uint16_t* Kh = Kb + (size_t)head * SQ * HN;
  const uint16_t* Vh = Vtb + (size_t)head * HN * SQ;

  // LDS (32 KB total): stage[hf][0]=K tile (P aliases it after QK),
  //                    stage[hf][1]=V tile. cacc aliases everything post-loop.
  __shared__ __align__(16) char smem_raw[32768];
  uint16_t (*stage)[2][64][64] = (uint16_t(*)[2][64][64])smem_raw;
  float (*cacc)[64][21]        = (float(*)[64][21])smem_raw;
  // per-wave P slice inside this group's K region: [16 rows][64 cols], swizzled
  uint16_t* pz = &stage[hf][0][wq * 16][0];

  const int lr8 = lane >> 3;            // row-within-8
  const int lc8 = lane & 7;             // phys 16B chunk
  const int sc8 = (lc8 - lr8) & 7;      // logical chunk this lane fetches

  // Q fragments, persistent
  bf16x8 aq0 = ldb8(Qh + (q0 + l16) * HN + quad * 8);
  bf16x8 aq1 = ldb8(Qh + (q0 + l16) * HN + 32 + quad * 8);

  float lrun[4];
  f32x4 acc[4];
#pragma unroll
  for (int r = 0; r < 4; ++r) {
    lrun[r] = 0.f;
    acc[r] = (f32x4){0.f, 0.f, 0.f, 0.f};
  }
  const float sc2 = 0.125f * 1.44269504f;   // 1/sqrt(64) * log2(e)

  for (int kt = 0; kt < 16; ++kt) {
    const int kbase = (hf * 16 + kt) * 64;
    // --- stage K tile rows + V^T tile rows for this half (4 gll16/wave) ---
#pragma unroll
    for (int j = 0; j < 2; ++j) {
      int rr = wq * 16 + j * 8;
      gll16(Kh + (size_t)(kbase + rr + lr8) * HN + sc8 * 8, &stage[hf][0][rr][0]);
      gll16(Vh + (size_t)(rr + lr8) * SQ + kbase + sc8 * 8, &stage[hf][1][rr][0]);
    }
    __syncthreads();   // (A) staging complete (vmcnt(0) before barrier)

    // --- S = Q K^T (frags straight from swizzled LDS) ---
    f32x4 s4[4];
#pragma unroll
    for (int st = 0; st < 4; ++st) {
      bf16x8 k0 = ldb8(&stage[hf][0][st * 16 + l16][0] + ((quad + l16) & 7) * 8);
      bf16x8 k1 = ldb8(&stage[hf][0][st * 16 + l16][0] + ((quad + 4 + l16) & 7) * 8);
      f32x4 z = (f32x4){0.f, 0.f, 0.f, 0.f};
      z = MFMA16(aq0, k0, z);
      s4[st] = MFMA16(aq1, k1, z);
    }
    __syncthreads();   // (B) all waves' K reads done -> K region reusable as P

    // --- exp2-domain softmax, P -> swizzled K-region slice, partial sums ---
#pragma unroll
    for (int st = 0; st < 4; ++st)
#pragma unroll
      for (int r = 0; r < 4; ++r) {
        float p = __builtin_amdgcn_exp2f(s4[st][r] * sc2);
        int row = quad * 4 + r;
        int phys = (st * 2 + (l16 >> 3) + row) & 7;
        pz[row * 64 + phys * 8 + (l16 & 7)] = f2bf_u(p);
        lrun[r] += p;
      }
    LGKM_DRAIN();      // same-wave DS ordering only
    bf16x8 ap0 = ldb8(pz + l16 * 64 + ((quad + l16) & 7) * 8);
    bf16x8 ap1 = ldb8(pz + l16 * 64 + ((quad + 4 + l16) & 7) * 8);
    // --- ctx += P @ V ---
#pragma unroll
    for (int dt = 0; dt < 4; ++dt) {
      bf16x8 v0 = ldb8(&stage[hf][1][dt * 16 + l16][0] + ((quad + l16) & 7) * 8);
      bf16x8 v1 = ldb8(&stage[hf][1][dt * 16 + l16][0] + ((quad + 4 + l16) & 7) * 8);
      acc[dt] = MFMA16(ap0, v0, acc[dt]);
      acc[dt] = MFMA16(ap1, v1, acc[dt]);
    }
    __syncthreads();   // (C) P & V reads done before next restaging
  }

  // --- k-split combine (linear: no max-tracking) via aliased LDS ---
  if (hf) {
    float* dst = cacc[wq][lane];
#pragma unroll
    for (int dt = 0; dt < 4; ++dt)
#pragma unroll
      for (int r = 0; r < 4; ++r) dst[dt * 4 + r] = acc[dt][r];
#pragma unroll
    for (int r = 0; r < 4; ++r) dst[16 + r] = lrun[r];
  }
  __syncthreads();
  if (hf) return;
  {
    const float* src = cacc[wq][lane];
#pragma unroll
    for (int dt = 0; dt < 4; ++dt)
#pragma unroll
      for (int r = 0; r < 4; ++r) acc[dt][r] += src[dt * 4 + r];
#pragma unroll
    for (int r = 0; r < 4; ++r) lrun[r] += src[16 + r];
  }

  // --- epilogue: 16-lane row-sum reduction, normalize, direct store ---
  float rinv[4];
#pragma unroll
  for (int r = 0; r < 4; ++r) {
    float ls = lrun[r];
    ls += __shfl_xor(ls, 1);
    ls += __shfl_xor(ls, 2);
    ls += __shfl_xor(ls, 4);
    ls += __shfl_xor(ls, 8);
    rinv[r] = __builtin_amdgcn_rcpf(ls);
  }
#pragma unroll
  for (int dt = 0; dt < 4; ++dt)
#pragma unroll
    for (int r = 0; r < 4; ++r) {
      int qg = q0 + quad * 4 + r;
      int dg = dt * 16 + l16;
      float v = acc[dt][r] * rinv[r];
      int row = qg * 2 + (head & 1);             // reference (nh,b) view scramble
      int col = (head >> 1) * HN + dg;
      ctxb[row * H + col] = f2bf_u(v);
    }
}

// ---------------------------------------------------------------------------
// Kernel 4: projection + bias, m97 structure (unchanged).
// ---------------------------------------------------------------------------
__global__ __launch_bounds__(256) void gemm_proj_kernel(
    const uint16_t* __restrict__ ab, const uint16_t* __restrict__ wb,
    const float* __restrict__ bias, float* __restrict__ out) {
  const int lane = threadIdx.x & 63;
  const int wave = threadIdx.x >> 6;
  const int quad = lane >> 4, l16 = lane & 15;
  const int row0 = blockIdx.y * 128, col0 = blockIdx.x * 64;

  __shared__ __align__(16) uint16_t sA[128 * 32];
  __shared__ __align__(16) uint16_t sB[64 * 32];

  const int lrow = lane >> 2;
  const int lk   = (lane & 3) * 8;

  f32x4 acc[2][4];
#pragma unroll
  for (int i = 0; i < 2; ++i)
#pragma unroll
    for (int j = 0; j < 4; ++j) acc[i][j] = (f32x4){0.f, 0.f, 0.f, 0.f};

  for (int k0 = 0; k0 < H; k0 += 32) {
#pragma unroll
    for (int c = 0; c < 2; ++c) {
      int g = c * 4 + wave;
      gll16(ab + (size_t)(row0 + g * 16 + lrow) * H + k0 + lk, sA + g * 512);
    }
    gll16(wb + (size_t)(col0 + wave * 16 + lrow) * H + k0 + lk, sB + wave * 512);
    __syncthreads();
    bf16x8 af[2], bfr[4];
#pragma unroll
    for (int mt = 0; mt < 2; ++mt)
      af[mt] = ldb8(sA + (wave * 32 + mt * 16 + l16) * 32 + quad * 8);
#pragma unroll
    for (int nt = 0; nt < 4; ++nt)
      bfr[nt] = ldb8(sB + (nt * 16 + l16) * 32 + quad * 8);
#pragma unroll
    for (int mt = 0; mt < 2; ++mt)
#pragma unroll
      for (int nt = 0; nt < 4; ++nt)
        acc[mt][nt] = MFMA16(af[mt], bfr[nt], acc[mt][nt]);
    __syncthreads();
  }

#pragma unroll
  for (int mt = 0; mt < 2; ++mt)
#pragma unroll
    for (int nt = 0; nt < 4; ++nt)
#pragma unroll
      for (int r = 0; r < 4; ++r) {
        int m = row0 + wave * 32 + mt * 16 + quad * 4 + r;  // t' = s*2+bi
        int c = col0 + nt * 16 + l16;
        int s = m >> 1, bi = m & 1;
        out[(size_t)(bi * SQ + s) * H + c] = acc[mt][nt][r] + bias[c];
      }
}

// ---------------------------------------------------------------------------
extern "C" void kernel_launch(void* const* d_in, const int* in_sizes, int n_in,
                              void* d_out, int out_size, void* d_ws, size_t ws_size,
                              hipStream_t stream) {
  const float* x     = (const float*)d_in[0];
  const float* wqkv  = (const float*)d_in[3];
  const float* wproj = (const float*)d_in[4];
  const float* bproj = (const float*)d_in[5];
  float* out = (float*)d_out;

  char* ws = (char*)d_ws;
  uint16_t* xb     = (uint16_t*)(ws);                        //  8 MB
  uint16_t* wqkvb  = (uint16_t*)(ws + (8ull  << 20));        //  6 MB
  uint16_t* wprojb = (uint16_t*)(ws + (14ull << 20));        //  2 MB
  uint16_t* Qb     = (uint16_t*)(ws + (16ull << 20));        //  8 MB [32][2048][64]
  uint16_t* Kb     = (uint16_t*)(ws + (24ull << 20));        //  8 MB [32][2048][64]
  uint16_t* Vtb    = (uint16_t*)(ws + (32ull << 20));        //  8 MB [32][64][2048]
  uint16_t* ctxb   = (uint16_t*)(ws + (40ull << 20));        //  8 MB [4096][1024]

  convert_kernel<<<8192, 256, 0, stream>>>(x, wqkv, wproj, xb, wqkvb, wprojb);
  gemm_qkv_kernel<<<dim3(N3H / 128, T_TOK / 128), 256, 0, stream>>>(xb, wqkvb, Qb, Kb, Vtb);
  attn_kernel<<<dim3(B_ * NH, SQ / 64), 512, 0, stream>>>(Qb, Kb, Vtb, ctxb);
  gemm_proj_kernel<<<dim3(H / 64, T_TOK / 128), 256, 0, stream>>>(ctxb, wprojb, bproj, out);
}

// Round 9
// 232.196 us; speedup vs baseline: 1.3006x; 1.3006x over previous
//
#include <hip/hip_runtime.h>
#include <stdint.h>

// Problem constants
#define B_   2
#define SQ   2048
#define H    1024
#define NH   16
#define HN   64
#define T_TOK 4096          // sq*b tokens
#define N3H  3072           // 3*h

typedef __bf16 bf16x8 __attribute__((ext_vector_type(8)));
typedef float  f32x4  __attribute__((ext_vector_type(4)));

#define MFMA16(a, b, c) __builtin_amdgcn_mfma_f32_16x16x32_bf16((a), (b), (c), 0, 0, 0)

// s_waitcnt lgkmcnt(0), vmcnt/expcnt left open (intrinsic form).
#define LGKM_DRAIN() do { \
  __builtin_amdgcn_s_waitcnt(0xC07F); \
  __builtin_amdgcn_wave_barrier(); \
} while (0)

__device__ __forceinline__ uint16_t f2bf_u(float f) {
  union { float f; uint32_t u; } v; v.f = f;
  uint32_t u = v.u;
  u += 0x7fffu + ((u >> 16) & 1u);   // RNE (no NaN inputs here)
  return (uint16_t)(u >> 16);
}

__device__ __forceinline__ bf16x8 ldb8(const uint16_t* p) {
  return *reinterpret_cast<const bf16x8*>(p);
}

// async global->LDS, 16B per lane. LDS dest = wave-uniform base + lane*16.
__device__ __forceinline__ void gll16(const uint16_t* g, uint16_t* l) {
  __builtin_amdgcn_global_load_lds(
      (const __attribute__((address_space(1))) uint32_t*)g,
      (__attribute__((address_space(3))) uint32_t*)l, 16, 0, 0);
}

// ---------------------------------------------------------------------------
// Kernel 1: fp32 -> bf16, 4 elements/thread.
// ---------------------------------------------------------------------------
__global__ __launch_bounds__(256) void convert_kernel(
    const float* __restrict__ x, const float* __restrict__ wqkv,
    const float* __restrict__ wproj,
    uint16_t* __restrict__ xb, uint16_t* __restrict__ wqkvb,
    uint16_t* __restrict__ wprojb) {
  const int XT4 = (T_TOK * H) / 4;   // 1048576
  const int WQ4 = (N3H * H) / 4;     // 786432
  int i4 = blockIdx.x * 256 + threadIdx.x;
  const float* src;
  uint16_t* dst;
  if (i4 < XT4) {
    int i = i4 * 4;
    int t = i >> 10, c = i & 1023;
    int bi = t & 1, s = t >> 1;
    src = x + (bi * SQ + s) * H + c;
    dst = xb + i;
  } else if (i4 < XT4 + WQ4) {
    int j = (i4 - XT4) * 4;
    src = wqkv + j; dst = wqkvb + j;
  } else {
    int j = (i4 - XT4 - WQ4) * 4;
    src = wproj + j; dst = wprojb + j;
  }
  float4 v = *(const float4*)src;
  ushort4 o;
  o.x = f2bf_u(v.x); o.y = f2bf_u(v.y); o.z = f2bf_u(v.z); o.w = f2bf_u(v.w);
  *(ushort4*)dst = o;
}

// ---------------------------------------------------------------------------
// Kernel 2: QKV GEMM, m97 structure + wave-uniform coalesced epilogue
// (unchanged from r7).
// ---------------------------------------------------------------------------
__global__ __launch_bounds__(256) void gemm_qkv_kernel(
    const uint16_t* __restrict__ xb, const uint16_t* __restrict__ wb,
    uint16_t* __restrict__ Qb, uint16_t* __restrict__ Kb,
    uint16_t* __restrict__ Vtb) {
  const int lane = threadIdx.x & 63;
  const int wave = threadIdx.x >> 6;
  const int quad = lane >> 4, l16 = lane & 15;
  const int wm = wave >> 1, wn = wave & 1;
  const int row0 = blockIdx.y * 128, col0 = blockIdx.x * 128;

  // union: staging (16 KB) and epilogue scratch (4 x 9728 B = 38912 B)
  __shared__ __align__(16) char smem[4 * 64 * 76 * 2];
  uint16_t* sA = (uint16_t*)smem;            // 128*32
  uint16_t* sB = (uint16_t*)(smem + 8192);   // 128*32
  uint16_t* W  = (uint16_t*)(smem) + wave * (64 * 76);

  const int lrow = lane >> 2;        // 0..15
  const int lk   = (lane & 3) * 8;   // k-chunk (8 elems = 16B)

  f32x4 acc[4][4];
#pragma unroll
  for (int i = 0; i < 4; ++i)
#pragma unroll
    for (int j = 0; j < 4; ++j) acc[i][j] = (f32x4){0.f, 0.f, 0.f, 0.f};

  for (int k0 = 0; k0 < H; k0 += 32) {
#pragma unroll
    for (int c = 0; c < 2; ++c) {
      int g = c * 4 + wave;
      gll16(xb + (size_t)(row0 + g * 16 + lrow) * H + k0 + lk, sA + g * 512);
      gll16(wb + (size_t)(col0 + g * 16 + lrow) * H + k0 + lk, sB + g * 512);
    }
    __syncthreads();
    bf16x8 af[4], bfr[4];
#pragma unroll
    for (int mt = 0; mt < 4; ++mt)
      af[mt] = ldb8(sA + (wm * 64 + mt * 16 + l16) * 32 + quad * 8);
#pragma unroll
    for (int nt = 0; nt < 4; ++nt)
      bfr[nt] = ldb8(sB + (wn * 64 + nt * 16 + l16) * 32 + quad * 8);
#pragma unroll
    for (int mt = 0; mt < 4; ++mt)
#pragma unroll
      for (int nt = 0; nt < 4; ++nt)
        acc[mt][nt] = MFMA16(af[mt], bfr[nt], acc[mt][nt]);
    __syncthreads();   // also protects smem reuse by the epilogue below
  }

  // ---- epilogue (wave-uniform routing; no divs, no branches per element) ---
  const int c0 = col0 + wn * 64;       // 64-aligned
  const int cm = c0 >> 6;              // 0..47
  const int hd = cm / 3;               // head (compile-time magic-mul)
  const int which = cm - hd * 3;       // 0=Q 1=K 2=V
  const int t0 = row0 + wm * 64;

  if (which < 2) {
    // LDS tile [t_local][d], stride 76
#pragma unroll
    for (int mt = 0; mt < 4; ++mt)
#pragma unroll
      for (int nt = 0; nt < 4; ++nt)
#pragma unroll
        for (int r = 0; r < 4; ++r)
          W[(mt * 16 + quad * 4 + r) * 76 + nt * 16 + l16] = f2bf_u(acc[mt][nt][r]);
    LGKM_DRAIN();
    uint16_t* dstb = (which == 0) ? Qb : Kb;
    const int t8 = lane >> 3, d0 = (lane & 7) * 8;
#pragma unroll
    for (int it = 0; it < 8; ++it) {
      int tl = it * 8 + t8;
      int t = t0 + tl;
      int s = t >> 1;
      int n = (t & 1) * NH + hd;
      bf16x8 vv = ldb8(W + tl * 76 + d0);
      *(bf16x8*)(dstb + (size_t)(n * SQ + s) * HN + d0) = vv;
    }
  } else {
    // V: LDS tile [d][bi*32 + s_local], stride 76; packed u32 writes
    uint32_t* W32 = (uint32_t*)W;
#pragma unroll
    for (int mt = 0; mt < 4; ++mt)
#pragma unroll
      for (int nt = 0; nt < 4; ++nt) {
        int base = (nt * 16 + l16) * 76 + mt * 8 + quad * 2;   // even
        W32[base >> 1] =
            (uint32_t)f2bf_u(acc[mt][nt][0]) | ((uint32_t)f2bf_u(acc[mt][nt][2]) << 16);
        W32[(base >> 1) + 16] =
            (uint32_t)f2bf_u(acc[mt][nt][1]) | ((uint32_t)f2bf_u(acc[mt][nt][3]) << 16);
      }
    LGKM_DRAIN();
    const int dl = lane >> 3;                 // 0..7
    const int bi = (lane >> 2) & 1;
    const int sc = (lane & 3) * 8;
    const int s0 = (row0 >> 1) + wm * 32;
    const int n = bi * NH + hd;
#pragma unroll
    for (int it = 0; it < 8; ++it) {
      int d = it * 8 + dl;
      bf16x8 vv = ldb8(W + d * 76 + bi * 32 + sc);
      *(bf16x8*)(Vtb + (size_t)(n * HN + d) * SQ + s0 + sc) = vv;
    }
  }
}

// ---------------------------------------------------------------------------
// Kernel 3: flash attention, k-split x2 + LDS K/V staging; P aliases the
// dead K-stage region (32 KB LDS total, conflict-free swizzle, r8 proven
// correct). launch_bounds back to (512,6): the (512,8) bound capped the
// UNIFIED arch+acc register file at 64/wave and spilled (r8: VGPR 32,
// FETCH 352 MB, 135 us; same law as r5). Natural allocation (~40 arch +
// 16 acc = 56 <= 64) already supports 8 waves/SIMD; residency comes from
// actual usage, so 32 KB LDS -> 4 blocks/CU x 8 waves = full one-pass grid.
// ---------------------------------------------------------------------------
__global__ __launch_bounds__(512, 6) void attn_kernel(
    const uint16_t* __restrict__ Qb, const uint16_t* __restrict__ Kb,
    const uint16_t* __restrict__ Vtb, uint16_t* __restrict__ ctxb) {
  const int lane = threadIdx.x & 63;
  const int wave = threadIdx.x >> 6;        // 0..7
  const int quad = lane >> 4, l16 = lane & 15;
  const int head  = blockIdx.x;   // n = bi*16 + hd
  const int qtile = blockIdx.y;
  const int wq = wave & 3;                  // q-subtile
  const int hf = wave >> 2;                 // k-range half
  const int q0 = qtile * 64 + wq * 16;

  const uint16_t* Qh = Qb + (size_t)head * SQ * HN;
  const uint16_t* Kh = Kb + (size_t)head * SQ * HN;
  const uint16_t* Vh = Vtb + (size_t)head * HN * SQ;

  // LDS (32 KB total): stage[hf][0]=K tile (P aliases it after QK),
  //                    stage[hf][1]=V tile. cacc aliases everything post-loop.
  __shared__ __align__(16) char smem_raw[32768];
  uint16_t (*stage)[2][64][64] = (uint16_t(*)[2][64][64])smem_raw;
  float (*cacc)[64][21]        = (float(*)[64][21])smem_raw;
  // per-wave P slice inside this group's K region: [16 rows][64 cols], swizzled
  uint16_t* pz = &stage[hf][0][wq * 16][0];

  const int lr8 = lane >> 3;            // row-within-8
  const int lc8 = lane & 7;             // phys 16B chunk
  const int sc8 = (lc8 - lr8) & 7;      // logical chunk this lane fetches

  // Q fragments, persistent
  bf16x8 aq0 = ldb8(Qh + (q0 + l16) * HN + quad * 8);
  bf16x8 aq1 = ldb8(Qh + (q0 + l16) * HN + 32 + quad * 8);

  float lrun[4];
  f32x4 acc[4];
#pragma unroll
  for (int r = 0; r < 4; ++r) {
    lrun[r] = 0.f;
    acc[r] = (f32x4){0.f, 0.f, 0.f, 0.f};
  }
  const float sc2 = 0.125f * 1.44269504f;   // 1/sqrt(64) * log2(e)

  for (int kt = 0; kt < 16; ++kt) {
    const int kbase = (hf * 16 + kt) * 64;
    // --- stage K tile rows + V^T tile rows for this half (4 gll16/wave) ---
#pragma unroll
    for (int j = 0; j < 2; ++j) {
      int rr = wq * 16 + j * 8;
      gll16(Kh + (size_t)(kbase + rr + lr8) * HN + sc8 * 8, &stage[hf][0][rr][0]);
      gll16(Vh + (size_t)(rr + lr8) * SQ + kbase + sc8 * 8, &stage[hf][1][rr][0]);
    }
    __syncthreads();   // (A) staging complete (vmcnt(0) before barrier)

    // --- S = Q K^T (frags straight from swizzled LDS) ---
    f32x4 s4[4];
#pragma unroll
    for (int st = 0; st < 4; ++st) {
      bf16x8 k0 = ldb8(&stage[hf][0][st * 16 + l16][0] + ((quad + l16) & 7) * 8);
      bf16x8 k1 = ldb8(&stage[hf][0][st * 16 + l16][0] + ((quad + 4 + l16) & 7) * 8);
      f32x4 z = (f32x4){0.f, 0.f, 0.f, 0.f};
      z = MFMA16(aq0, k0, z);
      s4[st] = MFMA16(aq1, k1, z);
    }
    __syncthreads();   // (B) all waves' K reads done -> K region reusable as P

    // --- exp2-domain softmax, P -> swizzled K-region slice, partial sums ---
#pragma unroll
    for (int st = 0; st < 4; ++st)
#pragma unroll
      for (int r = 0; r < 4; ++r) {
        float p = __builtin_amdgcn_exp2f(s4[st][r] * sc2);
        int row = quad * 4 + r;
        int phys = (st * 2 + (l16 >> 3) + row) & 7;
        pz[row * 64 + phys * 8 + (l16 & 7)] = f2bf_u(p);
        lrun[r] += p;
      }
    LGKM_DRAIN();      // same-wave DS ordering only
    bf16x8 ap0 = ldb8(pz + l16 * 64 + ((quad + l16) & 7) * 8);
    bf16x8 ap1 = ldb8(pz + l16 * 64 + ((quad + 4 + l16) & 7) * 8);
    // --- ctx += P @ V ---
#pragma unroll
    for (int dt = 0; dt < 4; ++dt) {
      bf16x8 v0 = ldb8(&stage[hf][1][dt * 16 + l16][0] + ((quad + l16) & 7) * 8);
      bf16x8 v1 = ldb8(&stage[hf][1][dt * 16 + l16][0] + ((quad + 4 + l16) & 7) * 8);
      acc[dt] = MFMA16(ap0, v0, acc[dt]);
      acc[dt] = MFMA16(ap1, v1, acc[dt]);
    }
    __syncthreads();   // (C) P & V reads done before next restaging
  }

  // --- k-split combine (linear: no max-tracking) via aliased LDS ---
  if (hf) {
    float* dst = cacc[wq][lane];
#pragma unroll
    for (int dt = 0; dt < 4; ++dt)
#pragma unroll
      for (int r = 0; r < 4; ++r) dst[dt * 4 + r] = acc[dt][r];
#pragma unroll
    for (int r = 0; r < 4; ++r) dst[16 + r] = lrun[r];
  }
  __syncthreads();
  if (hf) return;
  {
    const float* src = cacc[wq][lane];
#pragma unroll
    for (int dt = 0; dt < 4; ++dt)
#pragma unroll
      for (int r = 0; r < 4; ++r) acc[dt][r] += src[dt * 4 + r];
#pragma unroll
    for (int r = 0; r < 4; ++r) lrun[r] += src[16 + r];
  }

  // --- epilogue: 16-lane row-sum reduction, normalize, direct store ---
  float rinv[4];
#pragma unroll
  for (int r = 0; r < 4; ++r) {
    float ls = lrun[r];
    ls += __shfl_xor(ls, 1);
    ls += __shfl_xor(ls, 2);
    ls += __shfl_xor(ls, 4);
    ls += __shfl_xor(ls, 8);
    rinv[r] = __builtin_amdgcn_rcpf(ls);
  }
#pragma unroll
  for (int dt = 0; dt < 4; ++dt)
#pragma unroll
    for (int r = 0; r < 4; ++r) {
      int qg = q0 + quad * 4 + r;
      int dg = dt * 16 + l16;
      float v = acc[dt][r] * rinv[r];
      int row = qg * 2 + (head & 1);             // reference (nh,b) view scramble
      int col = (head >> 1) * HN + dg;
      ctxb[row * H + col] = f2bf_u(v);
    }
}

// ---------------------------------------------------------------------------
// Kernel 4: projection + bias, m97 structure (unchanged).
// ---------------------------------------------------------------------------
__global__ __launch_bounds__(256) void gemm_proj_kernel(
    const uint16_t* __restrict__ ab, const uint16_t* __restrict__ wb,
    const float* __restrict__ bias, float* __restrict__ out) {
  const int lane = threadIdx.x & 63;
  const int wave = threadIdx.x >> 6;
  const int quad = lane >> 4, l16 = lane & 15;
  const int row0 = blockIdx.y * 128, col0 = blockIdx.x * 64;

  __shared__ __align__(16) uint16_t sA[128 * 32];
  __shared__ __align__(16) uint16_t sB[64 * 32];

  const int lrow = lane >> 2;
  const int lk   = (lane & 3) * 8;

  f32x4 acc[2][4];
#pragma unroll
  for (int i = 0; i < 2; ++i)
#pragma unroll
    for (int j = 0; j < 4; ++j) acc[i][j] = (f32x4){0.f, 0.f, 0.f, 0.f};

  for (int k0 = 0; k0 < H; k0 += 32) {
#pragma unroll
    for (int c = 0; c < 2; ++c) {
      int g = c * 4 + wave;
      gll16(ab + (size_t)(row0 + g * 16 + lrow) * H + k0 + lk, sA + g * 512);
    }
    gll16(wb + (size_t)(col0 + wave * 16 + lrow) * H + k0 + lk, sB + wave * 512);
    __syncthreads();
    bf16x8 af[2], bfr[4];
#pragma unroll
    for (int mt = 0; mt < 2; ++mt)
      af[mt] = ldb8(sA + (wave * 32 + mt * 16 + l16) * 32 + quad * 8);
#pragma unroll
    for (int nt = 0; nt < 4; ++nt)
      bfr[nt] = ldb8(sB + (nt * 16 + l16) * 32 + quad * 8);
#pragma unroll
    for (int mt = 0; mt < 2; ++mt)
#pragma unroll
      for (int nt = 0; nt < 4; ++nt)
        acc[mt][nt] = MFMA16(af[mt], bfr[nt], acc[mt][nt]);
    __syncthreads();
  }

#pragma unroll
  for (int mt = 0; mt < 2; ++mt)
#pragma unroll
    for (int nt = 0; nt < 4; ++nt)
#pragma unroll
      for (int r = 0; r < 4; ++r) {
        int m = row0 + wave * 32 + mt * 16 + quad * 4 + r;  // t' = s*2+bi
        int c = col0 + nt * 16 + l16;
        int s = m >> 1, bi = m & 1;
        out[(size_t)(bi * SQ + s) * H + c] = acc[mt][nt][r] + bias[c];
      }
}

// ---------------------------------------------------------------------------
extern "C" void kernel_launch(void* const* d_in, const int* in_sizes, int n_in,
                              void* d_out, int out_size, void* d_ws, size_t ws_size,
                              hipStream_t stream) {
  const float* x     = (const float*)d_in[0];
  const float* wqkv  = (const float*)d_in[3];
  const float* wproj = (const float*)d_in[4];
  const float* bproj = (const float*)d_in[5];
  float* out = (float*)d_out;

  char* ws = (char*)d_ws;
  uint16_t* xb     = (uint16_t*)(ws);                        //  8 MB
  uint16_t* wqkvb  = (uint16_t*)(ws + (8ull  << 20));        //  6 MB
  uint16_t* wprojb = (uint16_t*)(ws + (14ull << 20));        //  2 MB
  uint16_t* Qb     = (uint16_t*)(ws + (16ull << 20));        //  8 MB [32][2048][64]
  uint16_t* Kb     = (uint16_t*)(ws + (24ull << 20));        //  8 MB [32][2048][64]
  uint16_t* Vtb    = (uint16_t*)(ws + (32ull << 20));        //  8 MB [32][64][2048]
  uint16_t* ctxb   = (uint16_t*)(ws + (40ull << 20));        //  8 MB [4096][1024]

  convert_kernel<<<8192, 256, 0, stream>>>(x, wqkv, wproj, xb, wqkvb, wprojb);
  gemm_qkv_kernel<<<dim3(N3H / 128, T_TOK / 128), 256, 0, stream>>>(xb, wqkvb, Qb, Kb, Vtb);
  attn_kernel<<<dim3(B_ * NH, SQ / 64), 512, 0, stream>>>(Qb, Kb, Vtb, ctxb);
  gemm_proj_kernel<<<dim3(H / 64, T_TOK / 128), 256, 0, stream>>>(ctxb, wprojb, bproj, out);
}